// Round 5
// baseline (2119.268 us; speedup 1.0000x reference)
//
#include <hip/hip_runtime.h>

// ---------------- ws layout (float offsets) ----------------
// [0]        : dtype flag (int: 1 = bf16 inputs, 0 = fp32 inputs)
// O_WC       : Wc = W1 @ W_enc   [64][128] fp32
// O_BC       : bc = W1 @ b_enc   [64] fp32
// O_BIAS     : bias = b_ih+b_hh  [1024] fp32
// O_BLEND1   : blend1 [1024][50][64] fp32
// O_XW       : xw [1024][50][1024] fp32 (200MB; only if ws_size permits)
#define O_WC     16
#define O_BC     (16 + 8192)
#define O_BIAS   (O_BC + 64)
#define O_BLEND1 16384
#define O_XW     4194304
#define XW_FLOATS 52428800ULL   // 1024*50*1024
#define NEG_INF_V (-1.0e9f)

typedef short bf16x8 __attribute__((ext_vector_type(8)));
typedef float f32x4  __attribute__((ext_vector_type(4)));

__device__ __forceinline__ float b2f(unsigned int u) {
  union { unsigned int i; float f; } x; x.i = u << 16; return x.f;
}
__device__ __forceinline__ unsigned short f2b(float f) {
  union { float f; unsigned int i; } x; x.f = f;
  unsigned int r = x.i + 0x7fffu + ((x.i >> 16) & 1u);
  return (unsigned short)(r >> 16);
}
__device__ __forceinline__ float ldv(const void* p, int b16, long long i) {
  if (b16) return b2f(((const unsigned short*)p)[i]);
  return ((const float*)p)[i];
}
__device__ __forceinline__ float sigm(float x)  { return 1.0f / (1.0f + __expf(-x)); }
__device__ __forceinline__ float tanhx(float x) { return 1.0f - 2.0f / (1.0f + __expf(2.0f * x)); }
// XOR swizzle: valid ONLY for the 8-slice x 8-chunk access pattern (s = lane&7,
// e0 = 64m + 8s). 16-slice patterns alias 4-way (round-3 regression) - don't.
__device__ __forceinline__ int SW(int j) { return j ^ ((j >> 3) & 7); }

// select bf16 element e (0..7) out of a uint4, e must be unroll-constant
__device__ __forceinline__ float bfsel(const uint4& u, int e) {
  unsigned int w = (e < 2) ? u.x : (e < 4) ? u.y : (e < 6) ? u.z : u.w;
  union { unsigned int i; float f; } x;
  x.i = (e & 1) ? (w & 0xffff0000u) : (w << 16);
  return x.f;
}
#define FMA4(A, F, H) { A.x += (F)*(H).x; A.y += (F)*(H).y; A.z += (F)*(H).z; A.w += (F)*(H).w; }

template<int NM, int LDW>
__device__ __forceinline__ void rows4_bf16(
    const unsigned short* W, int row0, int s, const float (*hb)[4],
    float4& a0, float4& a1, float4& a2, float4& a3) {
  const unsigned short* p0 = W + (long long)row0 * LDW + 8 * s;
  #pragma unroll 2
  for (int m = 0; m < NM; ++m) {
    const int e0 = 64 * m + 8 * s;
    uint4 w0 = *(const uint4*)(p0 + 64 * m);
    uint4 w1 = *(const uint4*)(p0 + LDW + 64 * m);
    uint4 w2 = *(const uint4*)(p0 + 2 * LDW + 64 * m);
    uint4 w3 = *(const uint4*)(p0 + 3 * LDW + 64 * m);
    #pragma unroll
    for (int e = 0; e < 8; ++e) {
      const float4 hv = *(const float4*)&hb[SW(e0 + e)][0];
      float f0 = bfsel(w0, e); FMA4(a0, f0, hv);
      float f1 = bfsel(w1, e); FMA4(a1, f1, hv);
      float f2 = bfsel(w2, e); FMA4(a2, f2, hv);
      float f3 = bfsel(w3, e); FMA4(a3, f3, hv);
    }
  }
}
template<int NM, int LDW>
__device__ __forceinline__ void rows4_f32(
    const float* W, int row0, int s, const float (*hb)[4],
    float4& a0, float4& a1, float4& a2, float4& a3) {
  #pragma unroll 2
  for (int m = 0; m < NM; ++m) {
    const int e0 = 64 * m + 8 * s;
    #pragma unroll
    for (int e = 0; e < 8; ++e) {
      const float4 hv = *(const float4*)&hb[SW(e0 + e)][0];
      float f0 = W[(long long)(row0 + 0) * LDW + e0 + e]; FMA4(a0, f0, hv);
      float f1 = W[(long long)(row0 + 1) * LDW + e0 + e]; FMA4(a1, f1, hv);
      float f2 = W[(long long)(row0 + 2) * LDW + e0 + e]; FMA4(a2, f2, hv);
      float f3 = W[(long long)(row0 + 3) * LDW + e0 + e]; FMA4(a3, f3, hv);
    }
  }
}

// ---------------- prepA: dtype detect + bias + bc (block 0) + Wc (blocks 1..32) ----
__global__ void prepA(const void* b_enc, const void* b_ih, const void* b_hh,
                      const void* W_enc, const void* W1, float* ws) {
  __shared__ int anybig;
  int t = threadIdx.x;
  if (t == 0) anybig = 0;
  __syncthreads();
  {
    unsigned short u = ((const unsigned short*)b_enc)[t];
    float f = b2f((unsigned int)u);
    if (!(fabsf(f) <= 1.0f)) atomicOr(&anybig, 1);
  }
  __syncthreads();
  int b16 = anybig ? 0 : 1;
  if (blockIdx.x == 0) {
    if (t == 0) ((int*)ws)[0] = b16;
    for (int k = t; k < 1024; k += 256)
      ws[O_BIAS + k] = ldv(b_ih, b16, k) + ldv(b_hh, b16, k);
    if (t < 64) {
      float acc = 0.f;
      for (int h = 0; h < 256; ++h)
        acc += ldv(W1, b16, t * 256 + h) * ldv(b_enc, b16, h);
      ws[O_BC + t] = acc;
    }
  } else {
    int o = (blockIdx.x - 1) * 256 + t;   // 0..8191
    int w = o >> 7, i = o & 127;
    float acc = 0.f;
    for (int h = 0; h < 256; ++h)
      acc += ldv(W1, b16, w * 256 + h) * ldv(W_enc, b16, h * 128 + i);
    ws[O_WC + o] = acc;
  }
}

// ---------------- blendk: blend1 = targets @ Wc^T + bc ----------------
__global__ __launch_bounds__(256) void blendk(const void* targets, float* ws) {
  __shared__ float tg[6400];
  int b16 = ((const int*)ws)[0];
  int t = threadIdx.x, b = blockIdx.x;
  if (b16) {
    const unsigned short* tp = (const unsigned short*)targets + (long long)b * 6400;
    for (int k = t * 8; k < 6400; k += 2048) {
      uint4 u = *(const uint4*)(tp + k);
      #pragma unroll
      for (int e = 0; e < 8; ++e) tg[k + e] = bfsel(u, e);
    }
  } else {
    const float* tp = (const float*)targets + (long long)b * 6400;
    for (int k = t; k < 6400; k += 256) tg[k] = tp[k];
  }
  __syncthreads();
  int w = t & 63, j0 = t >> 6;
  for (int j = j0; j < 50; j += 4) {
    float acc = 0.f;
    for (int i0 = 0; i0 < 128; i0 += 8) {
      const float4* q = (const float4*)(ws + O_WC + w * 128 + i0);
      float4 a = q[0], bb = q[1];
      const float* x = &tg[j * 128 + i0];
      acc += a.x * x[0] + a.y * x[1] + a.z * x[2] + a.w * x[3]
           + bb.x * x[4] + bb.y * x[5] + bb.z * x[6] + bb.w * x[7];
    }
    ws[O_BLEND1 + (b * 50 + j) * 64 + w] = acc + ws[O_BC + w];
  }
}

// ---------------- xwK: xw[b][j][r] = targets[b,j,:] . W_ih[r,:] ----------------
// bf16 path uses MFMA (bf16 x bf16 products are fp32-exact); fp32 path vector.
__global__ __launch_bounds__(256) void xwK(const void* targets, const void* W_ih,
                                           float* ws) {
  const int b = blockIdx.x, t = threadIdx.x;
  float* xwp = ws + O_XW + (unsigned long long)b * 51200ULL;
  if (((const int*)ws)[0]) {
    const int w = t >> 6, lane = t & 63;
    const int ln = lane & 15, kh = lane >> 4;     // n-within-tile, k-chunk
    const int m0 = w * 16;
    const unsigned short* tb = (const unsigned short*)targets + (long long)b * 6400;
    const unsigned short* wb = (const unsigned short*)W_ih;
    int arow = m0 + ln; if (arow > 49) arow = 49; // pad rows: clamp (not stored)
    bf16x8 afrag[4];
    #pragma unroll
    for (int ks = 0; ks < 4; ++ks) {
      uint4 u = *(const uint4*)(tb + arow * 128 + ks * 32 + kh * 8);
      afrag[ks] = *(bf16x8*)&u;
    }
    for (int n0 = 0; n0 < 1024; n0 += 16) {
      f32x4 acc = {0.f, 0.f, 0.f, 0.f};
      #pragma unroll
      for (int ks = 0; ks < 4; ++ks) {
        uint4 u = *(const uint4*)(wb + (long long)(n0 + ln) * 128 + ks * 32 + kh * 8);
        bf16x8 bfrag = *(bf16x8*)&u;
        acc = __builtin_amdgcn_mfma_f32_16x16x32_bf16(afrag[ks], bfrag, acc, 0, 0, 0);
      }
      #pragma unroll
      for (int r = 0; r < 4; ++r) {
        int j = m0 + kh * 4 + r;                  // D row = (lane>>4)*4 + reg
        if (j < 50) xwp[j * 1024 + n0 + ln] = acc[r];
      }
    }
  } else {
    __shared__ float tgl[64 * 132];
    __shared__ float wl[64 * 132];
    const float* tp = (const float*)targets + (long long)b * 6400;
    for (int k = t; k < 6400; k += 256) tgl[(k >> 7) * 132 + (k & 127)] = tp[k];
    for (int k = t; k < 14 * 132; k += 256) tgl[50 * 132 + k] = 0.f;
    const int tr = t & 15, tj = t >> 4;
    for (int c = 0; c < 16; ++c) {
      __syncthreads();
      const float* wp = (const float*)W_ih + (long long)c * 8192;
      for (int k = t; k < 8192; k += 256) wl[(k >> 7) * 132 + (k & 127)] = wp[k];
      __syncthreads();
      float a[4][4];
      #pragma unroll
      for (int rr = 0; rr < 4; rr++)
        #pragma unroll
        for (int jj = 0; jj < 4; jj++) a[rr][jj] = 0.f;
      for (int i0 = 0; i0 < 128; i0 += 4) {
        float4 wv0 = *(const float4*)&wl[(tr + 0)  * 132 + i0];
        float4 wv1 = *(const float4*)&wl[(tr + 16) * 132 + i0];
        float4 wv2 = *(const float4*)&wl[(tr + 32) * 132 + i0];
        float4 wv3 = *(const float4*)&wl[(tr + 48) * 132 + i0];
        #pragma unroll
        for (int jj = 0; jj < 4; jj++) {
          float4 tv = *(const float4*)&tgl[(tj + 16 * jj) * 132 + i0];
          a[0][jj] += wv0.x * tv.x + wv0.y * tv.y + wv0.z * tv.z + wv0.w * tv.w;
          a[1][jj] += wv1.x * tv.x + wv1.y * tv.y + wv1.z * tv.z + wv1.w * tv.w;
          a[2][jj] += wv2.x * tv.x + wv2.y * tv.y + wv2.z * tv.z + wv2.w * tv.w;
          a[3][jj] += wv3.x * tv.x + wv3.y * tv.y + wv3.z * tv.z + wv3.w * tv.w;
        }
      }
      #pragma unroll
      for (int jj = 0; jj < 4; jj++) {
        int j = tj + 16 * jj;
        if (j < 50) {
          #pragma unroll
          for (int rr = 0; rr < 4; rr++)
            xwp[j * 1024 + c * 64 + tr + 16 * rr] = a[rr][jj];
        }
      }
    }
  }
}

// ---------------- main: 50 sequential steps, 4 batch rows / block, 16 waves ----
// launch_bounds(1024,4): VGPR cap 128 (r2's proven fit); LDS ~87KB pins
// 1 block/CU so the allocator has no incentive to shrink regs below 128 (r3
// chose 64 chasing 2 blocks/CU and spilled).
__global__ __launch_bounds__(1024, 4) void mainK(
    const void* targets, const void* h0, const void* c0,
    const void* W_ih, const void* W_hh, const void* W2, const void* vt,
    float* ws, void* outp, int use_xw) {
  __shared__ __align__(16) float xT[128][4];
  __shared__ __align__(16) float hT[256][4];
  __shared__ float cT[4][256];
  __shared__ float gsh[4][1024];
  __shared__ float bias_s[1024];
  __shared__ float b2s[4][64];
  __shared__ float outs[4][64];
  __shared__ float vt_s[64];
  __shared__ int   selidx[4];
  __shared__ int   selb[4][64];
  __shared__ float bl1s[4 * 50 * 66];   // blend1, row stride 66 (2-way = free)

  const int b16 = ((const int*)ws)[0];
  const int t = threadIdx.x;
  const int bbase = blockIdx.x * 4;
  const float* xw = ws + O_XW;

  bias_s[t] = ws[O_BIAS + t];
  { int p = t & 3, j = t >> 2;
    hT[SW(j)][p] = ldv(h0, b16, (bbase + p) * 256 + j);
    cT[p][j]     = ldv(c0, b16, (bbase + p) * 256 + j); }
  if (t < 512) { int p = t & 3, i = t >> 2; xT[SW(i)][p] = 0.f; }
  if (t < 64) vt_s[t] = ldv(vt, b16, t);
  if (t >= 64 && t < 320) { int q = t - 64; selb[q >> 6][q & 63] = 0; }
  if (t >= 320 && t < 324) selidx[t - 320] = -1;
  // stage blend1 for this block's 4 batch rows into LDS
  for (int k = t; k < 12800; k += 1024) {
    int p = k >> 11, rem = k & 2047;          // k = p*3200 + ... careful: use div
    p = k / 3200; rem = k - p * 3200;
    int j = rem >> 6, w = rem & 63;
    bl1s[(p * 50 + j) * 66 + w] = ws[O_BLEND1 + (((bbase + p) * 50 + j) << 6) + w];
  }
  __syncthreads();

  const int s = t & 7, G = t >> 3;        // K-slice (0..7), row-group (0..127)
  const int lane = t & 63;

  // shuffle-reduce 4x float4 over the 8 K-slices, store gate rows row0..row0+3
  auto reduce_store = [&](float4 a0, float4 a1, float4 a2, float4 a3, int row0) {
    #pragma unroll
    for (int msk = 1; msk < 8; msk <<= 1) {
      a0.x += __shfl_xor(a0.x, msk, 64); a0.y += __shfl_xor(a0.y, msk, 64);
      a0.z += __shfl_xor(a0.z, msk, 64); a0.w += __shfl_xor(a0.w, msk, 64);
      a1.x += __shfl_xor(a1.x, msk, 64); a1.y += __shfl_xor(a1.y, msk, 64);
      a1.z += __shfl_xor(a1.z, msk, 64); a1.w += __shfl_xor(a1.w, msk, 64);
      a2.x += __shfl_xor(a2.x, msk, 64); a2.y += __shfl_xor(a2.y, msk, 64);
      a2.z += __shfl_xor(a2.z, msk, 64); a2.w += __shfl_xor(a2.w, msk, 64);
      a3.x += __shfl_xor(a3.x, msk, 64); a3.y += __shfl_xor(a3.y, msk, 64);
      a3.z += __shfl_xor(a3.z, msk, 64); a3.w += __shfl_xor(a3.w, msk, 64);
    }
    if (s < 4) {
      #pragma unroll
      for (int q = 0; q < 4; q++)
        if (s == q) {
          float4 aq = (q == 0) ? a0 : (q == 1) ? a1 : (q == 2) ? a2 : a3;
          gsh[0][row0 + q] = aq.x; gsh[1][row0 + q] = aq.y;
          gsh[2][row0 + q] = aq.z; gsh[3][row0 + q] = aq.w;
        }
    }
  };

  #pragma unroll 1
  for (int step = 0; step < 50; ++step) {
    // ---- phase A: gsh = h@W_hh^T (+ x@W_ih^T when no xw table) ----
    #pragma unroll 1
    for (int pass = 0; pass < 2; ++pass) {
      const int row0 = pass * 512 + G * 4;
      float4 a0 = {0,0,0,0}, a1 = {0,0,0,0}, a2 = {0,0,0,0}, a3 = {0,0,0,0};
      if (b16) {
        if (!use_xw)
          rows4_bf16<2,128>((const unsigned short*)W_ih, row0, s, xT, a0,a1,a2,a3);
        rows4_bf16<4,256>((const unsigned short*)W_hh, row0, s, hT, a0,a1,a2,a3);
      } else {
        if (!use_xw)
          rows4_f32<2,128>((const float*)W_ih, row0, s, xT, a0,a1,a2,a3);
        rows4_f32<4,256>((const float*)W_hh, row0, s, hT, a0,a1,a2,a3);
      }
      reduce_store(a0, a1, a2, a3, row0);
    }
    __syncthreads();

    // ---- phase A2: LSTM pointwise (adds gathered x@W_ih^T row) ----
    {
      int j = t & 255, p = t >> 8;
      float gi = gsh[p][j], gf = gsh[p][256 + j];
      float gg = gsh[p][512 + j], go = gsh[p][768 + j];
      if (use_xw) {
        int sv = selidx[p];
        if (sv >= 0) {
          const float* xr = xw + (((unsigned long long)(bbase + p)) * 50 + sv) * 1024ULL;
          gi += xr[j]; gf += xr[256 + j]; gg += xr[512 + j]; go += xr[768 + j];
        }
      }
      gi = sigm (gi + bias_s[j]);
      gf = sigm (gf + bias_s[256 + j]);
      gg = tanhx(gg + bias_s[512 + j]);
      go = sigm (go + bias_s[768 + j]);
      float c = gf * cT[p][j] + gi * gg;
      cT[p][j] = c;
      hT[SW(j)][p] = go * tanhx(c);
    }
    __syncthreads();

    // ---- blend2 = h @ W2^T (8-slice pattern: matches SW swizzle; t<512) ----
    if (t < 512) {
      float4 bq = {0,0,0,0};
      if (b16) {
        const unsigned short* p0 = (const unsigned short*)W2 + G * 256 + 8 * s;
        #pragma unroll 2
        for (int m = 0; m < 4; ++m) {
          const int e0 = 64 * m + 8 * s;
          uint4 w0 = *(const uint4*)(p0 + 64 * m);
          #pragma unroll
          for (int e = 0; e < 8; ++e) {
            const float4 hv = *(const float4*)&hT[SW(e0 + e)][0];
            float f0 = bfsel(w0, e); FMA4(bq, f0, hv);
          }
        }
      } else {
        const float* p0 = (const float*)W2 + G * 256;
        for (int m = 0; m < 4; ++m) {
          const int e0 = 64 * m + 8 * s;
          #pragma unroll
          for (int e = 0; e < 8; ++e) {
            const float4 hv = *(const float4*)&hT[SW(e0 + e)][0];
            float f0 = p0[e0 + e]; FMA4(bq, f0, hv);
          }
        }
      }
      #pragma unroll
      for (int msk = 1; msk < 8; msk <<= 1) {
        bq.x += __shfl_xor(bq.x, msk, 64); bq.y += __shfl_xor(bq.y, msk, 64);
        bq.z += __shfl_xor(bq.z, msk, 64); bq.w += __shfl_xor(bq.w, msk, 64);
      }
      if (s == 0) {
        b2s[0][G] = bq.x; b2s[1][G] = bq.y; b2s[2][G] = bq.z; b2s[3][G] = bq.w;
      }
    }
    __syncthreads();

    // ---- phase C: out = vt . tanh(blend1 + blend2), mask (800 thr) ----
    if (t < 800) {
      int o = t >> 2, sp = t & 3;
      int p = o / 50, j = o - p * 50;
      const float* bl = &bl1s[(p * 50 + j) * 66 + sp * 16];
      float acc = 0.f;
      #pragma unroll
      for (int w = 0; w < 16; w++)
        acc += vt_s[sp * 16 + w] * tanhx(bl[w] + b2s[p][sp * 16 + w]);
      acc += __shfl_xor(acc, 1, 64);
      acc += __shfl_xor(acc, 2, 64);
      if (sp == 0) outs[p][j] = selb[p][j] ? NEG_INF_V : acc;
    }
    __syncthreads();

    // ---- argmax + softmax + write probs, update selected ----
    if (t < 256) {
      int p = t >> 6;
      float v = (lane < 50) ? outs[p][lane] : -3.4e38f;
      int idx = lane;
      #pragma unroll
      for (int msk = 1; msk < 64; msk <<= 1) {
        float ov = __shfl_xor(v, msk, 64);
        int   oi = __shfl_xor(idx, msk, 64);
        if (ov > v || (ov == v && oi < idx)) { v = ov; idx = oi; }
      }
      float e = (lane < 50) ? __expf(outs[p][lane] - v) : 0.f;
      float ssum = e;
      #pragma unroll
      for (int msk = 1; msk < 64; msk <<= 1) ssum += __shfl_xor(ssum, msk, 64);
      if (lane < 50) {
        float prob = fmaxf(e / ssum, 1e-9f);
        int o = (bbase + p) * 2500 + step * 50 + lane;
        if (b16) ((unsigned short*)outp)[o] = f2b(prob);
        else     ((float*)outp)[o] = prob;
      }
      if (lane == 0) selidx[p] = idx;
      if (lane == idx) selb[p][idx] = 1;
    }
    __syncthreads();

    // ---- phase D (fallback only): dec_in gather into xT ----
    if (!use_xw) {
      if (t < 512) {
        int p = t >> 7, i = t & 127;
        xT[SW(i)][p] = ldv(targets, b16, ((long long)(bbase + p) * 50 + selidx[p]) * 128 + i);
      }
      __syncthreads();
    }
  }
}

extern "C" void kernel_launch(void* const* d_in, const int* in_sizes, int n_in,
                              void* d_out, int out_size, void* d_ws, size_t ws_size,
                              hipStream_t stream) {
  (void)in_sizes; (void)n_in; (void)out_size;
  const void* targets = d_in[0];
  const void* h0      = d_in[1];
  const void* c0      = d_in[2];
  const void* W_enc   = d_in[3];
  const void* b_enc   = d_in[4];
  const void* W_ih    = d_in[5];
  const void* W_hh    = d_in[6];
  const void* b_ih    = d_in[7];
  const void* b_hh    = d_in[8];
  const void* W1      = d_in[9];
  const void* W2      = d_in[10];
  const void* vt      = d_in[11];
  float* ws = (float*)d_ws;

  int use_xw = (ws_size >= ((size_t)O_XW + (size_t)XW_FLOATS) * 4) ? 1 : 0;

  prepA<<<33, 256, 0, stream>>>(b_enc, b_ih, b_hh, W_enc, W1, ws);
  if (use_xw) xwK<<<1024, 256, 0, stream>>>(targets, W_ih, ws);
  blendk<<<1024, 256, 0, stream>>>(targets, ws);
  mainK<<<256, 1024, 0, stream>>>(targets, h0, c0, W_ih, W_hh, W2, vt, ws, d_out,
                                  use_xw);
}

// Round 6
// 1762.940 us; speedup vs baseline: 1.2021x; 1.2021x over previous
//
#include <hip/hip_runtime.h>

// ---------------- ws layout (float offsets) ----------------
// [0]        : dtype flag (int: 1 = bf16 inputs, 0 = fp32 inputs)
// O_WC       : Wc = W1 @ W_enc   [64][128] fp32
// O_BC       : bc = W1 @ b_enc   [64] fp32
// O_BIAS     : bias = b_ih+b_hh  [1024] fp32
// O_WCH      : Wc as bf16 hi[64][128] then lo[64][128] (ushort)
// O_BLEND1   : blend1 [1024][50][64] fp32
// O_XW       : xw [1024][50][1024] fp32 (200MB; only if ws_size permits)
#define O_WC     16
#define O_BC     (16 + 8192)
#define O_BIAS   (O_BC + 64)
#define O_WCH    16384
#define O_BLEND1 32768
#define O_XW     4194304
#define XW_FLOATS 52428800ULL   // 1024*50*1024
#define NEG_INF_V (-1.0e9f)
#define GSTR 1092               // gsh row stride (dwords); 1092%32=4 -> conflict-free
#define ASTR 264                // hA row stride (bf16); 528B, 132 dw -> 2-way (free)

typedef short bf16x8 __attribute__((ext_vector_type(8)));
typedef float f32x4  __attribute__((ext_vector_type(4)));

__device__ __forceinline__ float b2f(unsigned int u) {
  union { unsigned int i; float f; } x; x.i = u << 16; return x.f;
}
__device__ __forceinline__ unsigned short f2b(float f) {
  union { float f; unsigned int i; } x; x.f = f;
  unsigned int r = x.i + 0x7fffu + ((x.i >> 16) & 1u);
  return (unsigned short)(r >> 16);
}
__device__ __forceinline__ float ldv(const void* p, int b16, long long i) {
  if (b16) return b2f(((const unsigned short*)p)[i]);
  return ((const float*)p)[i];
}
__device__ __forceinline__ float sigm(float x)  { return 1.0f / (1.0f + __expf(-x)); }
__device__ __forceinline__ float tanhx(float x) { return 1.0f - 2.0f / (1.0f + __expf(2.0f * x)); }
// XOR swizzle: valid ONLY for the 8-slice x 8-chunk pattern (fallback kernel).
__device__ __forceinline__ int SW(int j) { return j ^ ((j >> 3) & 7); }

__device__ __forceinline__ float bfsel(const uint4& u, int e) {
  unsigned int w = (e < 2) ? u.x : (e < 4) ? u.y : (e < 6) ? u.z : u.w;
  union { unsigned int i; float f; } x;
  x.i = (e & 1) ? (w & 0xffff0000u) : (w << 16);
  return x.f;
}
#define FMA4(A, F, H) { A.x += (F)*(H).x; A.y += (F)*(H).y; A.z += (F)*(H).z; A.w += (F)*(H).w; }

template<int NM, int LDW>
__device__ __forceinline__ void rows4_bf16(
    const unsigned short* W, int row0, int s, const float (*hb)[4],
    float4& a0, float4& a1, float4& a2, float4& a3) {
  const unsigned short* p0 = W + (long long)row0 * LDW + 8 * s;
  #pragma unroll 2
  for (int m = 0; m < NM; ++m) {
    const int e0 = 64 * m + 8 * s;
    uint4 w0 = *(const uint4*)(p0 + 64 * m);
    uint4 w1 = *(const uint4*)(p0 + LDW + 64 * m);
    uint4 w2 = *(const uint4*)(p0 + 2 * LDW + 64 * m);
    uint4 w3 = *(const uint4*)(p0 + 3 * LDW + 64 * m);
    #pragma unroll
    for (int e = 0; e < 8; ++e) {
      const float4 hv = *(const float4*)&hb[SW(e0 + e)][0];
      float f0 = bfsel(w0, e); FMA4(a0, f0, hv);
      float f1 = bfsel(w1, e); FMA4(a1, f1, hv);
      float f2 = bfsel(w2, e); FMA4(a2, f2, hv);
      float f3 = bfsel(w3, e); FMA4(a3, f3, hv);
    }
  }
}
template<int NM, int LDW>
__device__ __forceinline__ void rows4_f32(
    const float* W, int row0, int s, const float (*hb)[4],
    float4& a0, float4& a1, float4& a2, float4& a3) {
  #pragma unroll 2
  for (int m = 0; m < NM; ++m) {
    const int e0 = 64 * m + 8 * s;
    #pragma unroll
    for (int e = 0; e < 8; ++e) {
      const float4 hv = *(const float4*)&hb[SW(e0 + e)][0];
      float f0 = W[(long long)(row0 + 0) * LDW + e0 + e]; FMA4(a0, f0, hv);
      float f1 = W[(long long)(row0 + 1) * LDW + e0 + e]; FMA4(a1, f1, hv);
      float f2 = W[(long long)(row0 + 2) * LDW + e0 + e]; FMA4(a2, f2, hv);
      float f3 = W[(long long)(row0 + 3) * LDW + e0 + e]; FMA4(a3, f3, hv);
    }
  }
}

// ---------------- prepA: dtype detect + bias/bc (blk 0) + Wc fp32 & hi/lo ----
__global__ void prepA(const void* b_enc, const void* b_ih, const void* b_hh,
                      const void* W_enc, const void* W1, float* ws) {
  __shared__ int anybig;
  int t = threadIdx.x;
  if (t == 0) anybig = 0;
  __syncthreads();
  {
    unsigned short u = ((const unsigned short*)b_enc)[t];
    float f = b2f((unsigned int)u);
    if (!(fabsf(f) <= 1.0f)) atomicOr(&anybig, 1);
  }
  __syncthreads();
  int b16 = anybig ? 0 : 1;
  if (blockIdx.x == 0) {
    if (t == 0) ((int*)ws)[0] = b16;
    for (int k = t; k < 1024; k += 256)
      ws[O_BIAS + k] = ldv(b_ih, b16, k) + ldv(b_hh, b16, k);
    if (t < 64) {
      float acc = 0.f;
      for (int h = 0; h < 256; ++h)
        acc += ldv(W1, b16, t * 256 + h) * ldv(b_enc, b16, h);
      ws[O_BC + t] = acc;
    }
  } else {
    int o = (blockIdx.x - 1) * 256 + t;   // 0..8191 -> [w 0..63][i 0..127]
    int w = o >> 7, i = o & 127;
    float acc = 0.f;
    for (int h = 0; h < 256; ++h)
      acc += ldv(W1, b16, w * 256 + h) * ldv(W_enc, b16, h * 128 + i);
    ws[O_WC + o] = acc;
    unsigned short* wch = (unsigned short*)(ws + O_WCH);
    unsigned short hi = f2b(acc);
    wch[o] = hi;
    wch[8192 + o] = f2b(acc - b2f(hi));
  }
}

// -------- xwK: xw[b][j][r] = targets[b,j,:].W_ih[r,:]  AND blend1 (fused) ----
__global__ __launch_bounds__(256) void xwK(const void* targets, const void* W_ih,
                                           float* ws) {
  const int b = blockIdx.x, t = threadIdx.x;
  float* xwp = ws + O_XW + (unsigned long long)b * 51200ULL;
  if (((const int*)ws)[0]) {
    const int w = t >> 6, lane = t & 63;
    const int ln = lane & 15, kh = lane >> 4;
    const int m0 = w * 16;
    const unsigned short* tb = (const unsigned short*)targets + (long long)b * 6400;
    const unsigned short* wb = (const unsigned short*)W_ih;
    int arow = m0 + ln; if (arow > 49) arow = 49;
    bf16x8 afrag[4];
    #pragma unroll
    for (int ks = 0; ks < 4; ++ks) {
      uint4 u = *(const uint4*)(tb + arow * 128 + ks * 32 + kh * 8);
      afrag[ks] = *(bf16x8*)&u;
    }
    for (int n0 = 0; n0 < 1024; n0 += 16) {
      f32x4 acc = {0.f, 0.f, 0.f, 0.f};
      #pragma unroll
      for (int ks = 0; ks < 4; ++ks) {
        uint4 u = *(const uint4*)(wb + (long long)(n0 + ln) * 128 + ks * 32 + kh * 8);
        acc = __builtin_amdgcn_mfma_f32_16x16x32_bf16(afrag[ks], *(bf16x8*)&u, acc, 0, 0, 0);
      }
      #pragma unroll
      for (int r = 0; r < 4; ++r) {
        int j = m0 + kh * 4 + r;
        if (j < 50) xwp[j * 1024 + n0 + ln] = acc[r];
      }
    }
    // fused blend1 = targets @ Wc^T + bc  (Wc split hi/lo, same A-frags)
    const unsigned short* wch = (const unsigned short*)(ws + O_WCH);
    #pragma unroll 1
    for (int q = 0; q < 4; ++q) {
      f32x4 ah = {0.f,0.f,0.f,0.f}, al = {0.f,0.f,0.f,0.f};
      #pragma unroll
      for (int ks = 0; ks < 4; ++ks) {
        uint4 uh = *(const uint4*)(wch + (q * 16 + ln) * 128 + ks * 32 + kh * 8);
        uint4 ul = *(const uint4*)(wch + 8192 + (q * 16 + ln) * 128 + ks * 32 + kh * 8);
        ah = __builtin_amdgcn_mfma_f32_16x16x32_bf16(afrag[ks], *(bf16x8*)&uh, ah, 0, 0, 0);
        al = __builtin_amdgcn_mfma_f32_16x16x32_bf16(afrag[ks], *(bf16x8*)&ul, al, 0, 0, 0);
      }
      #pragma unroll
      for (int r = 0; r < 4; ++r) {
        int j = m0 + kh * 4 + r;
        if (j < 50)
          ws[O_BLEND1 + ((long long)b * 50 + j) * 64 + q * 16 + ln] =
              ah[r] + al[r] + ws[O_BC + q * 16 + ln];
      }
    }
  } else {
    // fp32 fallback: vector xw + blend1
    __shared__ float tgl[64 * 132];
    __shared__ float wl[64 * 132];
    const float* tp = (const float*)targets + (long long)b * 6400;
    for (int k = t; k < 6400; k += 256) tgl[(k >> 7) * 132 + (k & 127)] = tp[k];
    for (int k = t; k < 14 * 132; k += 256) tgl[50 * 132 + k] = 0.f;
    const int tr = t & 15, tj = t >> 4;
    for (int c = 0; c < 16; ++c) {
      __syncthreads();
      const float* wp = (const float*)W_ih + (long long)c * 8192;
      for (int k = t; k < 8192; k += 256) wl[(k >> 7) * 132 + (k & 127)] = wp[k];
      __syncthreads();
      float a[4][4];
      #pragma unroll
      for (int rr = 0; rr < 4; rr++)
        #pragma unroll
        for (int jj = 0; jj < 4; jj++) a[rr][jj] = 0.f;
      for (int i0 = 0; i0 < 128; i0 += 4) {
        float4 wv0 = *(const float4*)&wl[(tr + 0)  * 132 + i0];
        float4 wv1 = *(const float4*)&wl[(tr + 16) * 132 + i0];
        float4 wv2 = *(const float4*)&wl[(tr + 32) * 132 + i0];
        float4 wv3 = *(const float4*)&wl[(tr + 48) * 132 + i0];
        #pragma unroll
        for (int jj = 0; jj < 4; jj++) {
          float4 tv = *(const float4*)&tgl[(tj + 16 * jj) * 132 + i0];
          a[0][jj] += wv0.x * tv.x + wv0.y * tv.y + wv0.z * tv.z + wv0.w * tv.w;
          a[1][jj] += wv1.x * tv.x + wv1.y * tv.y + wv1.z * tv.z + wv1.w * tv.w;
          a[2][jj] += wv2.x * tv.x + wv2.y * tv.y + wv2.z * tv.z + wv2.w * tv.w;
          a[3][jj] += wv3.x * tv.x + wv3.y * tv.y + wv3.z * tv.z + wv3.w * tv.w;
        }
      }
      #pragma unroll
      for (int jj = 0; jj < 4; jj++) {
        int j = tj + 16 * jj;
        if (j < 50) {
          #pragma unroll
          for (int rr = 0; rr < 4; rr++)
            xwp[j * 1024 + c * 64 + tr + 16 * rr] = a[rr][jj];
        }
      }
    }
    __syncthreads();
    int w2 = t & 63, j0 = t >> 6;
    for (int j = j0; j < 50; j += 4) {
      float acc = 0.f;
      for (int i0 = 0; i0 < 128; i0 += 4) {
        const float4 wv = *(const float4*)(ws + O_WC + w2 * 128 + i0);
        const float4 tv = *(const float4*)&tgl[j * 132 + i0];
        acc += wv.x * tv.x + wv.y * tv.y + wv.z * tv.z + wv.w * tv.w;
      }
      ws[O_BLEND1 + ((long long)b * 50 + j) * 64 + w2] = acc + ws[O_BC + w2];
    }
  }
}

// ---------------- mainMF: MFMA step loop, 8 batch rows/block, 128 blocks ----
// gates+blend2 in ONE MFMA pass: A rows 0-7 = h_hi (batch), 8-15 = h_lo;
// B = [W_hh(1024) ; W2(64)] rows. D row p + row p+8 (shfl_xor 32) = fp32 gates.
__global__ __launch_bounds__(512) void mainMF(
    const void* h0, const void* c0, const void* W_hh, const void* W2,
    const void* vt, float* ws, void* outp, int use_xw) {
  const int b16 = ((const int*)ws)[0];
  if (!(b16 && use_xw)) return;     // fallback kernel covers

  __shared__ unsigned short hA[16 * ASTR];   // A-operand layout, hi rows 0-7, lo 8-15
  __shared__ float gsh[8 * GSTR];            // [batch][cols]; 0-1023 gates, 1024-1087 blend2
  __shared__ float cT[8][256];
  __shared__ float bias_s[1024];
  __shared__ float outs[8][64];
  __shared__ float vt_s[64];
  __shared__ int   selidx[8];
  __shared__ int   selb[8][64];

  const int t = threadIdx.x;
  const int bbase = blockIdx.x * 8;
  const float* xw = ws + O_XW;
  const unsigned short* Whh = (const unsigned short*)W_hh;
  const unsigned short* W2p = (const unsigned short*)W2;

  for (int k = t; k < 1024; k += 512) bias_s[k] = ws[O_BIAS + k];
  for (int k = t; k < 2048; k += 512) {
    int p = k >> 8, j = k & 255;
    float h = b2f(((const unsigned short*)h0)[(bbase + p) * 256 + j]);
    unsigned short hi = f2b(h);
    hA[p * ASTR + j] = hi;
    hA[(8 + p) * ASTR + j] = f2b(h - b2f(hi));
    cT[p][j] = b2f(((const unsigned short*)c0)[(bbase + p) * 256 + j]);
  }
  if (t < 64) vt_s[t] = b2f(((const unsigned short*)vt)[t]);
  selb[t >> 6][t & 63] = 0;
  if (t < 8) selidx[t] = -1;
  __syncthreads();

  const int lane = t & 63, wv = t >> 6;
  const int ln = lane & 15, kh = lane >> 4;

  #pragma unroll 1
  for (int step = 0; step < 50; ++step) {
    // ---- xw prefetch (uses selidx from prev argmax; overlaps MFMA) ----
    float xpre[16];
    #pragma unroll
    for (int g = 0; g < 4; ++g) {
      const int k = g * 512 + t, p = k >> 8, j = k & 255;
      const int sv = selidx[p];
      const float* xr = xw + (((unsigned long long)(bbase + p)) * 50 +
                              (sv < 0 ? 0 : sv)) * 1024ULL + j;
      const bool on = sv >= 0;
      xpre[g * 4 + 0] = on ? xr[0]   : 0.f;
      xpre[g * 4 + 1] = on ? xr[256] : 0.f;
      xpre[g * 4 + 2] = on ? xr[512] : 0.f;
      xpre[g * 4 + 3] = on ? xr[768] : 0.f;
    }

    // ---- MFMA: gates + blend2 ----
    bf16x8 af[8];
    #pragma unroll
    for (int kt = 0; kt < 8; ++kt) {
      uint4 u = *(const uint4*)&hA[(lane & 15) * ASTR + kt * 32 + kh * 8];
      af[kt] = *(bf16x8*)&u;
    }
    #pragma unroll 1
    for (int i = 0; i < 9; ++i) {
      if (i == 8 && wv >= 4) break;
      const int gcol = (i < 8) ? (wv * 8 + i) * 16 : 1024 + wv * 16;
      const unsigned short* bp = (i < 8) ? (Whh + (gcol + ln) * 256)
                                         : (W2p + (wv * 16 + ln) * 256);
      f32x4 acc = {0.f, 0.f, 0.f, 0.f};
      #pragma unroll
      for (int kt = 0; kt < 8; ++kt) {
        uint4 bu = *(const uint4*)(bp + kt * 32 + kh * 8);
        acc = __builtin_amdgcn_mfma_f32_16x16x32_bf16(af[kt], *(bf16x8*)&bu, acc, 0, 0, 0);
      }
      #pragma unroll
      for (int r = 0; r < 4; ++r) {
        float v = acc[r] + __shfl_xor(acc[r], 32, 64);
        if (lane < 32) gsh[((lane >> 4) * 4 + r) * GSTR + gcol + ln] = v;
      }
    }
    __syncthreads();

    // ---- A2: LSTM pointwise (gsh + xw + bias) -> c, h -> hA hi/lo ----
    #pragma unroll
    for (int g = 0; g < 4; ++g) {
      const int k = g * 512 + t, p = k >> 8, j = k & 255;
      float gi = sigm (gsh[p * GSTR + j]       + xpre[g * 4 + 0] + bias_s[j]);
      float gf = sigm (gsh[p * GSTR + 256 + j] + xpre[g * 4 + 1] + bias_s[256 + j]);
      float gg = tanhx(gsh[p * GSTR + 512 + j] + xpre[g * 4 + 2] + bias_s[512 + j]);
      float go = sigm (gsh[p * GSTR + 768 + j] + xpre[g * 4 + 3] + bias_s[768 + j]);
      float c = gf * cT[p][j] + gi * gg;
      cT[p][j] = c;
      float h = go * tanhx(c);
      unsigned short hi = f2b(h);
      hA[p * ASTR + j] = hi;
      hA[(8 + p) * ASTR + j] = f2b(h - b2f(hi));
    }
    // ---- C: out = vt . tanh(blend1 + blend2), mask (no barrier needed:
    //      reads gsh cols 1024+ (pre-barrier) & global blend1; A2 doesn't touch)
    if (t < 400) {
      const int p = t / 50, j = t - p * 50;
      const float* bl = ws + O_BLEND1 + (((long long)(bbase + p)) * 50 + j) * 64;
      float acc = 0.f;
      #pragma unroll 4
      for (int w = 0; w < 64; ++w)
        acc += vt_s[w] * tanhx(bl[w] + gsh[p * GSTR + 1024 + w]);
      outs[p][j] = selb[p][j] ? NEG_INF_V : acc;
    }
    __syncthreads();

    // ---- argmax + softmax + write probs, update selected (all 512 thr) ----
    {
      const int p = t >> 6;
      float v = (lane < 50) ? outs[p][lane] : -3.4e38f;
      int idx = lane;
      #pragma unroll
      for (int msk = 1; msk < 64; msk <<= 1) {
        float ov = __shfl_xor(v, msk, 64);
        int   oi = __shfl_xor(idx, msk, 64);
        if (ov > v || (ov == v && oi < idx)) { v = ov; idx = oi; }
      }
      float e = (lane < 50) ? __expf(outs[p][lane] - v) : 0.f;
      float ssum = e;
      #pragma unroll
      for (int msk = 1; msk < 64; msk <<= 1) ssum += __shfl_xor(ssum, msk, 64);
      if (lane < 50) {
        float prob = fmaxf(e / ssum, 1e-9f);
        long long o = ((long long)(bbase + p)) * 2500 + step * 50 + lane;
        ((unsigned short*)outp)[o] = f2b(prob);
      }
      if (lane == 0) selidx[p] = idx;
      if (lane == idx) selb[p][idx] = 1;
    }
    __syncthreads();
  }
}

// ---------------- mainFB: r2 vector fallback (fp32 inputs or no xw table) ----
__global__ __launch_bounds__(512) void mainFB(
    const void* targets, const void* h0, const void* c0,
    const void* W_ih, const void* W_hh, const void* W2, const void* vt,
    float* ws, void* outp, int use_xw) {
  const int b16 = ((const int*)ws)[0];
  if (b16 && use_xw) return;        // mainMF covers
  __shared__ __align__(16) float xT[128][4];
  __shared__ __align__(16) float hT[256][4];
  __shared__ float cT[4][256];
  __shared__ float gsh[4][1024];
  __shared__ float bias_s[1024];
  __shared__ float b2s[4][64];
  __shared__ float outs[4][64];
  __shared__ float vt_s[64];
  __shared__ int   selidx[4];
  __shared__ int   selb[4][64];

  const int t = threadIdx.x;
  const int bbase = blockIdx.x * 4;
  const float* xw = ws + O_XW;

  for (int k = t; k < 1024; k += 512) bias_s[k] = ws[O_BIAS + k];
  for (int k = t; k < 1024; k += 512) {
    int p = k & 3, j = k >> 2;
    hT[SW(j)][p] = ldv(h0, b16, (bbase + p) * 256 + j);
    cT[p][j]     = ldv(c0, b16, (bbase + p) * 256 + j);
  }
  { int p = t & 3, i = t >> 2; xT[SW(i)][p] = 0.f; }
  if (t < 64) vt_s[t] = ldv(vt, b16, t);
  if (t < 256) selb[t >> 6][t & 63] = 0;
  if (t < 4) selidx[t] = -1;
  __syncthreads();

  const int s = t & 7, G = t >> 3;
  const int lane = t & 63;

  auto reduce_store = [&](float4 a0, float4 a1, float4 a2, float4 a3, int row0) {
    #pragma unroll
    for (int msk = 1; msk < 8; msk <<= 1) {
      a0.x += __shfl_xor(a0.x, msk, 64); a0.y += __shfl_xor(a0.y, msk, 64);
      a0.z += __shfl_xor(a0.z, msk, 64); a0.w += __shfl_xor(a0.w, msk, 64);
      a1.x += __shfl_xor(a1.x, msk, 64); a1.y += __shfl_xor(a1.y, msk, 64);
      a1.z += __shfl_xor(a1.z, msk, 64); a1.w += __shfl_xor(a1.w, msk, 64);
      a2.x += __shfl_xor(a2.x, msk, 64); a2.y += __shfl_xor(a2.y, msk, 64);
      a2.z += __shfl_xor(a2.z, msk, 64); a2.w += __shfl_xor(a2.w, msk, 64);
      a3.x += __shfl_xor(a3.x, msk, 64); a3.y += __shfl_xor(a3.y, msk, 64);
      a3.z += __shfl_xor(a3.z, msk, 64); a3.w += __shfl_xor(a3.w, msk, 64);
    }
    if (s < 4) {
      #pragma unroll
      for (int q = 0; q < 4; q++)
        if (s == q) {
          float4 aq = (q == 0) ? a0 : (q == 1) ? a1 : (q == 2) ? a2 : a3;
          gsh[0][row0 + q] = aq.x; gsh[1][row0 + q] = aq.y;
          gsh[2][row0 + q] = aq.z; gsh[3][row0 + q] = aq.w;
        }
    }
  };

  #pragma unroll 1
  for (int step = 0; step < 50; ++step) {
    #pragma unroll 1
    for (int pass = 0; pass < 4; ++pass) {
      const int row0 = pass * 256 + G * 4;
      float4 a0 = {0,0,0,0}, a1 = {0,0,0,0}, a2 = {0,0,0,0}, a3 = {0,0,0,0};
      if (b16) {
        if (!use_xw)
          rows4_bf16<2,128>((const unsigned short*)W_ih, row0, s, xT, a0,a1,a2,a3);
        rows4_bf16<4,256>((const unsigned short*)W_hh, row0, s, hT, a0,a1,a2,a3);
      } else {
        if (!use_xw)
          rows4_f32<2,128>((const float*)W_ih, row0, s, xT, a0,a1,a2,a3);
        rows4_f32<4,256>((const float*)W_hh, row0, s, hT, a0,a1,a2,a3);
      }
      reduce_store(a0, a1, a2, a3, row0);
    }
    __syncthreads();

    for (int k = t; k < 1024; k += 512) {
      int j = k & 255, p = k >> 8;
      float gi = gsh[p][j], gf = gsh[p][256 + j];
      float gg = gsh[p][512 + j], go = gsh[p][768 + j];
      if (use_xw) {
        int sv = selidx[p];
        if (sv >= 0) {
          const float* xr = xw + (((unsigned long long)(bbase + p)) * 50 + sv) * 1024ULL;
          gi += xr[j]; gf += xr[256 + j]; gg += xr[512 + j]; go += xr[768 + j];
        }
      }
      gi = sigm (gi + bias_s[j]);
      gf = sigm (gf + bias_s[256 + j]);
      gg = tanhx(gg + bias_s[512 + j]);
      go = sigm (go + bias_s[768 + j]);
      float c = gf * cT[p][j] + gi * gg;
      cT[p][j] = c;
      hT[SW(j)][p] = go * tanhx(c);
    }
    __syncthreads();

    {
      float4 bq = {0,0,0,0};
      if (b16) {
        const unsigned short* p0 = (const unsigned short*)W2 + G * 256 + 8 * s;
        #pragma unroll 2
        for (int m = 0; m < 4; ++m) {
          const int e0 = 64 * m + 8 * s;
          uint4 w0 = *(const uint4*)(p0 + 64 * m);
          #pragma unroll
          for (int e = 0; e < 8; ++e) {
            const float4 hv = *(const float4*)&hT[SW(e0 + e)][0];
            float f0 = bfsel(w0, e); FMA4(bq, f0, hv);
          }
        }
      } else {
        const float* p0 = (const float*)W2 + G * 256;
        for (int m = 0; m < 4; ++m) {
          const int e0 = 64 * m + 8 * s;
          #pragma unroll
          for (int e = 0; e < 8; ++e) {
            const float4 hv = *(const float4*)&hT[SW(e0 + e)][0];
            float f0 = p0[e0 + e]; FMA4(bq, f0, hv);
          }
        }
      }
      #pragma unroll
      for (int msk = 1; msk < 8; msk <<= 1) {
        bq.x += __shfl_xor(bq.x, msk, 64); bq.y += __shfl_xor(bq.y, msk, 64);
        bq.z += __shfl_xor(bq.z, msk, 64); bq.w += __shfl_xor(bq.w, msk, 64);
      }
      if (s == 0) {
        b2s[0][G] = bq.x; b2s[1][G] = bq.y; b2s[2][G] = bq.z; b2s[3][G] = bq.w;
      }
    }
    __syncthreads();

    if (t < 400) {
      int o = t >> 1, sp = t & 1;
      int p = o / 50, j = o - p * 50;
      const float* bl = ws + O_BLEND1 + (((bbase + p) * 50 + j) * 64) + sp * 32;
      float acc = 0.f;
      #pragma unroll 8
      for (int w = 0; w < 32; w++)
        acc += vt_s[sp * 32 + w] * tanhx(bl[w] + b2s[p][sp * 32 + w]);
      acc += __shfl_xor(acc, 1, 64);
      if (sp == 0) outs[p][j] = selb[p][j] ? NEG_INF_V : acc;
    }
    __syncthreads();

    if (t < 256) {
      int p = t >> 6;
      float v = (lane < 50) ? outs[p][lane] : -3.4e38f;
      int idx = lane;
      #pragma unroll
      for (int msk = 1; msk < 64; msk <<= 1) {
        float ov = __shfl_xor(v, msk, 64);
        int   oi = __shfl_xor(idx, msk, 64);
        if (ov > v || (ov == v && oi < idx)) { v = ov; idx = oi; }
      }
      float e = (lane < 50) ? __expf(outs[p][lane] - v) : 0.f;
      float ssum = e;
      #pragma unroll
      for (int msk = 1; msk < 64; msk <<= 1) ssum += __shfl_xor(ssum, msk, 64);
      if (lane < 50) {
        float prob = fmaxf(e / ssum, 1e-9f);
        int o = (bbase + p) * 2500 + step * 50 + lane;
        if (b16) ((unsigned short*)outp)[o] = f2b(prob);
        else     ((float*)outp)[o] = prob;
      }
      if (lane == 0) selidx[p] = idx;
      if (lane == idx) selb[p][idx] = 1;
    }
    __syncthreads();

    if (!use_xw) {
      int p = t >> 7, i = t & 127;
      xT[SW(i)][p] = ldv(targets, b16, ((long long)(bbase + p) * 50 + selidx[p]) * 128 + i);
      __syncthreads();
    }
  }
}

extern "C" void kernel_launch(void* const* d_in, const int* in_sizes, int n_in,
                              void* d_out, int out_size, void* d_ws, size_t ws_size,
                              hipStream_t stream) {
  (void)in_sizes; (void)n_in; (void)out_size;
  const void* targets = d_in[0];
  const void* h0      = d_in[1];
  const void* c0      = d_in[2];
  const void* W_enc   = d_in[3];
  const void* b_enc   = d_in[4];
  const void* W_ih    = d_in[5];
  const void* W_hh    = d_in[6];
  const void* b_ih    = d_in[7];
  const void* b_hh    = d_in[8];
  const void* W1      = d_in[9];
  const void* W2      = d_in[10];
  const void* vt      = d_in[11];
  float* ws = (float*)d_ws;

  int use_xw = (ws_size >= ((size_t)O_XW + (size_t)XW_FLOATS) * 4) ? 1 : 0;

  prepA<<<33, 256, 0, stream>>>(b_enc, b_ih, b_hh, W_enc, W1, ws);
  if (use_xw) xwK<<<1024, 256, 0, stream>>>(targets, W_ih, ws);
  mainMF<<<128, 512, 0, stream>>>(h0, c0, W_hh, W2, vt, ws, d_out, use_xw);
  mainFB<<<256, 512, 0, stream>>>(targets, h0, c0, W_ih, W_hh, W2, vt, ws, d_out,
                                  use_xw);
}